// Round 1
// baseline (451.039 us; speedup 1.0000x reference)
//
#include <hip/hip_runtime.h>

#define THRESH 0.5f
#define ALPHA 0.5f
#define BLOCK 256

// One pass over (B*N) rows of 5 floats from each of x,y.
// Per row: p=x[.,0], t=y[.,0], m=(t>THRESH)
//   accumulate: cnt += m
//               s_se  += m * sum((x[1:5]-y[1:5])^2)
//               s_bce += m * -(t*log(p) + (1-t)*log1p(-p))
//               s_bg  += -log1p(-p)
__global__ void mloss_partial(const float* __restrict__ x,
                              const float* __restrict__ y,
                              float* __restrict__ ws,
                              int ngroups, int nrows) {
    float cnt = 0.f, s_se = 0.f, s_bce = 0.f, s_bg = 0.f;
    const int stride = gridDim.x * blockDim.x;
    const int tid = blockIdx.x * blockDim.x + threadIdx.x;

    auto row = [&](float p, float t, float d0, float d1, float d2, float d3) {
        float l1m = log1pf(-p);          // log(1-p)
        s_bg -= l1m;
        float m = (t > THRESH) ? 1.f : 0.f;
        cnt += m;
        float se = d0*d0 + d1*d1 + d2*d2 + d3*d3;
        s_se += m * se;
        float bce = -(t * logf(p) + (1.f - t) * l1m);
        s_bce += m * bce;
    };

    // Vectorized path: 4 rows = 20 floats = 5 float4 per input (80B-aligned).
    for (int g = tid; g < ngroups; g += stride) {
        const float4* xv = (const float4*)(x + (size_t)g * 20);
        const float4* yv = (const float4*)(y + (size_t)g * 20);
        float4 a0 = xv[0], a1 = xv[1], a2 = xv[2], a3 = xv[3], a4 = xv[4];
        float4 b0 = yv[0], b1 = yv[1], b2 = yv[2], b3 = yv[3], b4 = yv[4];

        row(a0.x, b0.x, a0.y-b0.y, a0.z-b0.z, a0.w-b0.w, a1.x-b1.x);
        row(a1.y, b1.y, a1.z-b1.z, a1.w-b1.w, a2.x-b2.x, a2.y-b2.y);
        row(a2.z, b2.z, a2.w-b2.w, a3.x-b3.x, a3.y-b3.y, a3.z-b3.z);
        row(a3.w, b3.w, a4.x-b4.x, a4.y-b4.y, a4.z-b4.z, a4.w-b4.w);
    }

    // Scalar tail (nrows not divisible by 4; empty for this problem shape).
    for (int r = ngroups * 4 + tid; r < nrows; r += stride) {
        const float* xr = x + (size_t)r * 5;
        const float* yr = y + (size_t)r * 5;
        row(xr[0], yr[0], xr[1]-yr[1], xr[2]-yr[2], xr[3]-yr[3], xr[4]-yr[4]);
    }

    // Wave-64 butterfly reduce.
    #pragma unroll
    for (int off = 32; off > 0; off >>= 1) {
        cnt   += __shfl_down(cnt,   off);
        s_se  += __shfl_down(s_se,  off);
        s_bce += __shfl_down(s_bce, off);
        s_bg  += __shfl_down(s_bg,  off);
    }
    if ((threadIdx.x & 63) == 0) {
        atomicAdd(&ws[0], cnt);
        atomicAdd(&ws[1], s_se);
        atomicAdd(&ws[2], s_bce);
        atomicAdd(&ws[3], s_bg);
    }
}

__global__ void mloss_final(const float* __restrict__ ws,
                            float* __restrict__ out,
                            float inv_total) {
    float f = ws[0];
    float scale = 1.f + 1.f / f;
    float diff_box = scale * ws[1] / (f * 4.f);
    float diff_c   = scale * ws[2] / f;
    float diff_bg  = ALPHA * ws[3] * inv_total;
    out[0] = diff_box + diff_c + diff_bg;
}

extern "C" void kernel_launch(void* const* d_in, const int* in_sizes, int n_in,
                              void* d_out, int out_size, void* d_ws, size_t ws_size,
                              hipStream_t stream) {
    const float* x = (const float*)d_in[0];
    const float* y = (const float*)d_in[1];
    float* out = (float*)d_out;
    float* ws  = (float*)d_ws;

    int total  = in_sizes[0];        // B*N*C = 27,688,960
    int nrows  = total / 5;          // 5,537,792
    int ngroups = nrows / 4;         // 1,384,448 (exact for this shape)

    hipMemsetAsync(ws, 0, 4 * sizeof(float), stream);

    int grid = (ngroups + BLOCK - 1) / BLOCK;
    if (grid > 2048) grid = 2048;
    mloss_partial<<<grid, BLOCK, 0, stream>>>(x, y, ws, ngroups, nrows);
    mloss_final<<<1, 1, 0, stream>>>(ws, out, 1.0f / (float)nrows);
}

// Round 2
// 48.550 us; speedup vs baseline: 9.2902x; 9.2902x over previous
//
#include <hip/hip_runtime.h>

#define THRESH 0.5f
#define ALPHA 0.5f
#define BLOCK 256
#define MAXGRID 2048

// Stage 1: streaming fused reduction. Each block writes ONE float4 partial
// (cnt, s_se, s_bce, s_bg) to its own ws slot -- no atomics (fp32 atomicAdd
// lowers to a CAS loop on gfx950; 32K same-address CAS was 457us in R1).
__global__ void mloss_partial(const float* __restrict__ x,
                              const float* __restrict__ y,
                              float4* __restrict__ part,
                              int ngroups, int nrows) {
    float cnt = 0.f, s_se = 0.f, s_bce = 0.f, s_bg = 0.f;
    const int stride = gridDim.x * blockDim.x;
    const int tid = blockIdx.x * blockDim.x + threadIdx.x;

    auto row = [&](float p, float t, float d0, float d1, float d2, float d3) {
        float l1m = log1pf(-p);          // log(1-p)
        s_bg -= l1m;
        float m = (t > THRESH) ? 1.f : 0.f;
        cnt += m;
        float se = d0*d0 + d1*d1 + d2*d2 + d3*d3;
        s_se += m * se;
        float bce = -(t * logf(p) + (1.f - t) * l1m);
        s_bce += m * bce;
    };

    // 4 rows = 20 floats = 5 float4 per input (80B per thread-group).
    for (int g = tid; g < ngroups; g += stride) {
        const float4* xv = (const float4*)(x + (size_t)g * 20);
        const float4* yv = (const float4*)(y + (size_t)g * 20);
        float4 a0 = xv[0], a1 = xv[1], a2 = xv[2], a3 = xv[3], a4 = xv[4];
        float4 b0 = yv[0], b1 = yv[1], b2 = yv[2], b3 = yv[3], b4 = yv[4];

        row(a0.x, b0.x, a0.y-b0.y, a0.z-b0.z, a0.w-b0.w, a1.x-b1.x);
        row(a1.y, b1.y, a1.z-b1.z, a1.w-b1.w, a2.x-b2.x, a2.y-b2.y);
        row(a2.z, b2.z, a2.w-b2.w, a3.x-b3.x, a3.y-b3.y, a3.z-b3.z);
        row(a3.w, b3.w, a4.x-b4.x, a4.y-b4.y, a4.z-b4.z, a4.w-b4.w);
    }

    // Scalar tail (empty for this shape; kept for robustness).
    for (int r = ngroups * 4 + tid; r < nrows; r += stride) {
        const float* xr = x + (size_t)r * 5;
        const float* yr = y + (size_t)r * 5;
        row(xr[0], yr[0], xr[1]-yr[1], xr[2]-yr[2], xr[3]-yr[3], xr[4]-yr[4]);
    }

    // Wave-64 butterfly reduce.
    #pragma unroll
    for (int off = 32; off > 0; off >>= 1) {
        cnt   += __shfl_down(cnt,   off);
        s_se  += __shfl_down(s_se,  off);
        s_bce += __shfl_down(s_bce, off);
        s_bg  += __shfl_down(s_bg,  off);
    }

    __shared__ float4 lds[BLOCK / 64];
    const int wid = threadIdx.x >> 6;
    if ((threadIdx.x & 63) == 0)
        lds[wid] = make_float4(cnt, s_se, s_bce, s_bg);
    __syncthreads();
    if (threadIdx.x == 0) {
        float4 a = lds[0];
        #pragma unroll
        for (int w = 1; w < BLOCK / 64; ++w) {
            a.x += lds[w].x; a.y += lds[w].y; a.z += lds[w].z; a.w += lds[w].w;
        }
        part[blockIdx.x] = a;   // unconditional write: deterministic, no stale ws
    }
}

// Stage 2: one block reduces nparts float4 partials and emits the scalar.
__global__ void mloss_final(const float4* __restrict__ part, int nparts,
                            float* __restrict__ out, float inv_total) {
    float cnt = 0.f, s_se = 0.f, s_bce = 0.f, s_bg = 0.f;
    for (int i = threadIdx.x; i < nparts; i += BLOCK) {
        float4 v = part[i];
        cnt += v.x; s_se += v.y; s_bce += v.z; s_bg += v.w;
    }
    #pragma unroll
    for (int off = 32; off > 0; off >>= 1) {
        cnt   += __shfl_down(cnt,   off);
        s_se  += __shfl_down(s_se,  off);
        s_bce += __shfl_down(s_bce, off);
        s_bg  += __shfl_down(s_bg,  off);
    }
    __shared__ float4 lds[BLOCK / 64];
    const int wid = threadIdx.x >> 6;
    if ((threadIdx.x & 63) == 0)
        lds[wid] = make_float4(cnt, s_se, s_bce, s_bg);
    __syncthreads();
    if (threadIdx.x == 0) {
        float4 a = lds[0];
        #pragma unroll
        for (int w = 1; w < BLOCK / 64; ++w) {
            a.x += lds[w].x; a.y += lds[w].y; a.z += lds[w].z; a.w += lds[w].w;
        }
        float f = a.x;
        float scale = 1.f + 1.f / f;
        float diff_box = scale * a.y / (f * 4.f);
        float diff_c   = scale * a.z / f;
        float diff_bg  = ALPHA * a.w * inv_total;
        out[0] = diff_box + diff_c + diff_bg;
    }
}

extern "C" void kernel_launch(void* const* d_in, const int* in_sizes, int n_in,
                              void* d_out, int out_size, void* d_ws, size_t ws_size,
                              hipStream_t stream) {
    const float* x = (const float*)d_in[0];
    const float* y = (const float*)d_in[1];
    float* out  = (float*)d_out;
    float4* part = (float4*)d_ws;

    int total   = in_sizes[0];       // B*N*C = 27,688,960
    int nrows   = total / 5;         // 5,537,792
    int ngroups = nrows / 4;         // 1,384,448 (exact for this shape)

    int grid = (ngroups + BLOCK - 1) / BLOCK;
    if (grid > MAXGRID) grid = MAXGRID;

    mloss_partial<<<grid, BLOCK, 0, stream>>>(x, y, part, ngroups, nrows);
    mloss_final<<<1, BLOCK, 0, stream>>>(part, grid, out, 1.0f / (float)nrows);
}

// Round 3
// 41.914 us; speedup vs baseline: 10.7611x; 1.1583x over previous
//
#include <hip/hip_runtime.h>

#define THRESH 0.5f
#define ALPHA 0.5f
#define BLOCK 256

// Fully-coalesced streaming reduction.
//
// Layout: rows of 5 floats. 4 rows = 20 floats = 5 float4. A float4 with
// index j has phase p = j % 5; channel of slot s is (4p+s) % 5.
//   p=0: [c0 c1 c2 c3]   p=1: [c4|c0 c1 c2]   p=2: [c3 c4|c0 c1]
//   p=3: [c2 c3 c4|c0]   p=4: [c1 c2 c3 c4]
// Each float4 holds at most one c0 (slot s == p, for p < 4). Box elements
// with s < p belong to the PREVIOUS row, whose mask comes from the previous
// float4 (lane-1, same register) -> one __shfl_up(1) carry per register.
// Tiles of 320 float4 (= 64 row-groups) per wave keep tile boundaries on
// row-group boundaries (320 % 5 == 0) -> no cross-tile carry.
__global__ void mloss_partial(const float4* __restrict__ xv,
                              const float4* __restrict__ yv,
                              const float* __restrict__ x,
                              const float* __restrict__ y,
                              float4* __restrict__ part,
                              int ntiles, int nrows) {
    float cnt = 0.f, s_se = 0.f, s_bce = 0.f, s_bg = 0.f;
    const int lane   = threadIdx.x & 63;
    const int gwave  = (blockIdx.x * BLOCK + threadIdx.x) >> 6;
    const int nwaves = (gridDim.x * BLOCK) >> 6;

    // Loop-invariant per-lane phases: p[k] = (lane + 64k) % 5.
    int p[5];
    {
        const int add[5] = {0, 4, 3, 2, 1};   // (64k) % 5
        int lm5 = lane % 5;
        #pragma unroll
        for (int k = 0; k < 5; ++k) {
            int v = lm5 + add[k];
            p[k] = (v >= 5) ? v - 5 : v;
        }
    }

    for (int tile = gwave; tile < ntiles; tile += nwaves) {
        size_t f0 = (size_t)tile * 320 + lane;
        float4 X[5], Y[5];
        #pragma unroll
        for (int k = 0; k < 5; ++k) {
            X[k] = xv[f0 + 64 * k];           // perfectly coalesced
            Y[k] = yv[f0 + 64 * k];
        }

        float carry = 0.f;                    // my_m of (reg k-1, lane 63)
        #pragma unroll
        for (int k = 0; k < 5; ++k) {
            const int pk = p[k];
            const float4 Xk = X[k], Yk = Y[k];

            // c0 (p,t) pair of this float4 (slot pk; pk==4 -> dummy slot 3,
            // value in (0.01,0.99) so transcendentals stay finite; zeroed below).
            float my_t = (pk == 0) ? Yk.x : (pk == 1) ? Yk.y : (pk == 2) ? Yk.z : Yk.w;
            float my_p = (pk == 0) ? Xk.x : (pk == 1) ? Xk.y : (pk == 2) ? Xk.z : Xk.w;
            float my_m = (my_t > THRESH) ? 1.f : 0.f;

            float pm_up  = __shfl_up(my_m, 1);
            float prev_m = (lane == 0) ? carry : pm_up;
            carry = __shfl(my_m, 63);

            float has = (pk < 4) ? 1.f : 0.f;
            float l1m = __logf(1.f - my_p);   // log(1-p); p<=0.99 -> exact enough
            float lg  = __logf(my_p);
            s_bg -= has * l1m;
            float hm = has * my_m;
            cnt += hm;
            s_bce -= hm * (my_t * lg + (1.f - my_t) * l1m);

            // Box slots: w = 0 if c0 slot, else mask of the owning row.
            float d, w;
            d = Xk.x - Yk.x; w = (pk == 0) ? 0.f : ((0 < pk) ? prev_m : my_m); s_se += w * d * d;
            d = Xk.y - Yk.y; w = (pk == 1) ? 0.f : ((1 < pk) ? prev_m : my_m); s_se += w * d * d;
            d = Xk.z - Yk.z; w = (pk == 2) ? 0.f : ((2 < pk) ? prev_m : my_m); s_se += w * d * d;
            d = Xk.w - Yk.w; w = (pk == 3) ? 0.f : ((3 < pk) ? prev_m : my_m); s_se += w * d * d;
        }
    }

    // Generic scalar tail (zero iterations for this shape).
    for (int r = ntiles * 256 + blockIdx.x * BLOCK + threadIdx.x; r < nrows;
         r += gridDim.x * BLOCK) {
        const float* xr = x + (size_t)r * 5;
        const float* yr = y + (size_t)r * 5;
        float pp = xr[0], tt = yr[0];
        float m = (tt > THRESH) ? 1.f : 0.f;
        float l1m = __logf(1.f - pp);
        s_bg -= l1m;
        cnt += m;
        s_bce -= m * (tt * __logf(pp) + (1.f - tt) * l1m);
        float d1 = xr[1]-yr[1], d2 = xr[2]-yr[2], d3 = xr[3]-yr[3], d4 = xr[4]-yr[4];
        s_se += m * (d1*d1 + d2*d2 + d3*d3 + d4*d4);
    }

    // Wave-64 butterfly reduce.
    #pragma unroll
    for (int off = 32; off > 0; off >>= 1) {
        cnt   += __shfl_down(cnt,   off);
        s_se  += __shfl_down(s_se,  off);
        s_bce += __shfl_down(s_bce, off);
        s_bg  += __shfl_down(s_bg,  off);
    }

    __shared__ float4 lds[BLOCK / 64];
    const int wid = threadIdx.x >> 6;
    if ((threadIdx.x & 63) == 0)
        lds[wid] = make_float4(cnt, s_se, s_bce, s_bg);
    __syncthreads();
    if (threadIdx.x == 0) {
        float4 a = lds[0];
        #pragma unroll
        for (int w = 1; w < BLOCK / 64; ++w) {
            a.x += lds[w].x; a.y += lds[w].y; a.z += lds[w].z; a.w += lds[w].w;
        }
        part[blockIdx.x] = a;                 // unconditional: deterministic
    }
}

// Stage 2: one block reduces the per-block partials and emits the scalar.
__global__ void mloss_final(const float4* __restrict__ part, int nparts,
                            float* __restrict__ out, float inv_total) {
    float cnt = 0.f, s_se = 0.f, s_bce = 0.f, s_bg = 0.f;
    for (int i = threadIdx.x; i < nparts; i += BLOCK) {
        float4 v = part[i];
        cnt += v.x; s_se += v.y; s_bce += v.z; s_bg += v.w;
    }
    #pragma unroll
    for (int off = 32; off > 0; off >>= 1) {
        cnt   += __shfl_down(cnt,   off);
        s_se  += __shfl_down(s_se,  off);
        s_bce += __shfl_down(s_bce, off);
        s_bg  += __shfl_down(s_bg,  off);
    }
    __shared__ float4 lds[BLOCK / 64];
    const int wid = threadIdx.x >> 6;
    if ((threadIdx.x & 63) == 0)
        lds[wid] = make_float4(cnt, s_se, s_bce, s_bg);
    __syncthreads();
    if (threadIdx.x == 0) {
        float4 a = lds[0];
        #pragma unroll
        for (int w = 1; w < BLOCK / 64; ++w) {
            a.x += lds[w].x; a.y += lds[w].y; a.z += lds[w].z; a.w += lds[w].w;
        }
        float f = a.x;
        float scale = 1.f + 1.f / f;
        float diff_box = scale * a.y / (f * 4.f);
        float diff_c   = scale * a.z / f;
        float diff_bg  = ALPHA * a.w * inv_total;
        out[0] = diff_box + diff_c + diff_bg;
    }
}

extern "C" void kernel_launch(void* const* d_in, const int* in_sizes, int n_in,
                              void* d_out, int out_size, void* d_ws, size_t ws_size,
                              hipStream_t stream) {
    const float* x = (const float*)d_in[0];
    const float* y = (const float*)d_in[1];
    float* out   = (float*)d_out;
    float4* part = (float4*)d_ws;

    int total  = in_sizes[0];        // B*N*C = 27,688,960
    int nrows  = total / 5;          // 5,537,792
    int ntiles = total / 1280;       // 21,632 tiles of 320 float4 (exact here)

    // Target 2 tiles per wave (exact balance for this shape: grid = 2704).
    int waves_needed = (ntiles + 1) / 2;
    int grid = (waves_needed + 3) / 4;         // 4 waves per 256-thread block
    if (grid < 256) grid = 256;
    if (grid > 4096) grid = 4096;
    int wscap = (int)(ws_size / sizeof(float4));
    if (grid > wscap) grid = wscap;

    mloss_partial<<<grid, BLOCK, 0, stream>>>((const float4*)x, (const float4*)y,
                                              x, y, part, ntiles, nrows);
    mloss_final<<<1, BLOCK, 0, stream>>>(part, grid, out, 1.0f / (float)nrows);
}